// Round 6
// baseline (238.289 us; speedup 1.0000x reference)
//
#include <hip/hip_runtime.h>
#include <math.h>

#define L2E  1.4426950408889634f
#define TL2E 2.8853900817779268f   // 2*log2(e)
#define HSTR 136   // h LDS row stride (bf16): 272B, 16B-aligned fragments

typedef __bf16 bf16x8 __attribute__((ext_vector_type(8)));
typedef float  f32x4  __attribute__((ext_vector_type(4)));

__device__ __forceinline__ float sig2(float y) {  // sigmoid(x), y = x*log2e
    return __builtin_amdgcn_rcpf(1.0f + __builtin_amdgcn_exp2f(-y));
}

// ================= single fused kernel =================
// 256 blocks x 512 thr (8 waves, 2/SIMD, 256-VGPR budget -> no spill).
// Wave w owns col-tile m0=w*16 for ALL 4 gates. R1-proven loop skeleton:
// af[4] upfront, per-gate MFMA chains (F first), 8-trans independent-chain tail,
// next-step acc-init hoisted into the MFMA shadow. One barrier per step.
__global__ __launch_bounds__(512, 2) void lstm_kernel(
        const float* __restrict__ numbers,
        const float* __restrict__ w_num, const float* __restrict__ b_num,
        const float* __restrict__ W_ih,  const float* __restrict__ W_hh,
        const float* __restrict__ b_ih,  const float* __restrict__ b_hh,
        const float* __restrict__ W_fh,  const float* __restrict__ b_fh,
        const float* __restrict__ W_iouh, const float* __restrict__ b_iouh,
        const float* __restrict__ W_lout, const float* __restrict__ b_lout,
        float* __restrict__ partials, int* __restrict__ flag,
        float* __restrict__ out) {
    __shared__ unsigned short hbuf[2][16 * HSTR];
    __shared__ float xls[129 * 16];           // +1 t-slot: harmless OOB read by hoisted init at t=127
    __shared__ float abw[1024];               // A[0..511], B[512..1023] (log2e-folded)
    __shared__ float wnb[256];                // w_num, b_num
    __shared__ float sx[100], lutm[100], luti[100];
    __shared__ float fin[768];                // hsb fcs iou hfin
    __shared__ float s_m99, s_i99;
    __shared__ int s_last;

    const int tid  = threadIdx.x;
    const int lane = tid & 63;
    const int wave = tid >> 6;        // 0..7
    const int quad = lane >> 4;
    const int lcol = lane & 15;
    const int m0   = wave * 16;
    const int r0   = blockIdx.x * 16;

    // ---- stage small vectors, zero h0 ----
    if (tid < 128) wnb[tid] = w_num[tid];
    else if (tid < 256) wnb[tid] = b_num[tid - 128];
    if (tid < 100) sx[tid] = numbers[tid];
    for (int i = tid; i < 16 * HSTR; i += 512) hbuf[0][i] = 0;
    __syncthreads();

    // stats over first 100 numbers (k=100 stats, used by all flats >= 100)
    if (wave == 0) {
        float v1 = sx[lane];
        float v2 = (lane < 36) ? sx[64 + lane] : 0.0f;
        float s = v1 + v2, ss = v1 * v1 + v2 * v2;
        #pragma unroll
        for (int off = 32; off >= 1; off >>= 1) {
            s += __shfl_xor(s, off);
            ss += __shfl_xor(ss, off);
        }
        if (lane == 0) {
            float mean = s * 0.01f;
            float var  = ss * 0.01f - mean * mean;
            if (var < 0.f) var = 0.f;
            float sd = sqrtf(var);
            s_m99 = mean;
            s_i99 = (sd > 1e-8f) ? (1.0f / sd) : 1.0f;
        }
    }
    if (blockIdx.x == 0 && tid < 100) {   // per-k LUT: only block 0's rows use it
        float s = 0.f, ss = 0.f;
        for (int j = 0; j <= tid; ++j) { float v = sx[j]; s += v; ss += v * v; }
        float cap  = (float)(tid + 1);
        float mean = s / cap;
        float var  = ss / cap - mean * mean;
        if (var < 0.f) var = 0.f;
        float sd = sqrtf(var);
        lutm[tid] = mean;
        luti[tid] = (cap > 3.0f && sd > 1e-8f) ? (1.0f / sd) : 1.0f;
    }
    // rank-1 input vectors (2-acc ILP to halve the latency-bound dot)
    {
        int j = tid;
        const float* row = W_ih + j * 256 + 128;
        float a0 = 0.f, a1 = 0.f, b0 = 0.f, b1 = 0.f;
        #pragma unroll 4
        for (int m = 0; m < 128; m += 8) {
            f32x4 w0 = *(const f32x4*)(row + m);
            f32x4 w1 = *(const f32x4*)(row + m + 4);
            f32x4 n0 = *(const f32x4*)(wnb + m);
            f32x4 n1 = *(const f32x4*)(wnb + m + 4);
            f32x4 c0 = *(const f32x4*)(wnb + 128 + m);
            f32x4 c1 = *(const f32x4*)(wnb + 132 + m);
            a0 += w0[0]*n0[0] + w0[1]*n0[1] + w0[2]*n0[2] + w0[3]*n0[3];
            a1 += w1[0]*n1[0] + w1[1]*n1[1] + w1[2]*n1[2] + w1[3]*n1[3];
            b0 += w0[0]*c0[0] + w0[1]*c0[1] + w0[2]*c0[2] + w0[3]*c0[3];
            b1 += w1[0]*c1[0] + w1[1]*c1[1] + w1[2]*c1[2] + w1[3]*c1[3];
        }
        float sc = (j >= 256 && j < 384) ? TL2E : L2E;
        abw[j]       = (a0 + a1) * sc;
        abw[512 + j] = (b0 + b1 + b_ih[j] + b_hh[j]) * sc;
    }
    __syncthreads();

    // normalize x into xls [t][row]
    for (int i = tid; i < 2048; i += 512) {
        int row = i >> 7, t = i & 127;
        int flat = (r0 + row) * 128 + t;
        float v = numbers[flat];
        float mn, iv;
        if (flat < 100) { mn = lutm[flat]; iv = luti[flat]; }
        else            { mn = s_m99;     iv = s_i99; }
        xls[t * 16 + row] = (v - mn) * iv;
    }

    // persistent W_hh B-fragments (bf16, log2e-folded): 64 VGPRs
    bf16x8 bfr[4][4];
    #pragma unroll
    for (int g = 0; g < 4; ++g) {
        float sc = (g == 2) ? TL2E : L2E;
        #pragma unroll
        for (int kk = 0; kk < 4; ++kk) {
            const float* p = W_hh + (g * 128 + m0 + lcol) * 128 + kk * 32 + quad * 8;
            f32x4 w0 = *(const f32x4*)p;
            f32x4 w1 = *(const f32x4*)(p + 4);
            bf16x8 bt;
            #pragma unroll
            for (int q = 0; q < 4; ++q) {
                bt[q]     = (__bf16)(w0[q] * sc);
                bt[q + 4] = (__bf16)(w1[q] * sc);
            }
            bfr[g][kk] = bt;
        }
    }
    float ag[4], bg[4];
    #pragma unroll
    for (int g = 0; g < 4; ++g) {
        ag[g] = abw[g * 128 + m0 + lcol];
        bg[g] = abw[512 + g * 128 + m0 + lcol];
    }
    float cst[4] = {0.f, 0.f, 0.f, 0.f};
    __syncthreads();

    // pre-compute acc-init for t=0
    f32x4 nI, nF, nG, nO;
    {
        f32x4 xq = *(const f32x4*)(const void*)(xls + quad * 4);
        #pragma unroll
        for (int r = 0; r < 4; ++r) {
            nI[r] = xq[r] * ag[0] + bg[0];
            nF[r] = xq[r] * ag[1] + bg[1];
            nG[r] = xq[r] * ag[2] + bg[2];
            nO[r] = xq[r] * ag[3] + bg[3];
        }
    }

    auto step = [&](int t, const unsigned short* hin, unsigned short* hout) {
        const unsigned short* hp = hin + lcol * HSTR + quad * 8;
        bf16x8 af0 = *(const bf16x8*)(const void*)(hp);
        bf16x8 af1 = *(const bf16x8*)(const void*)(hp + 32);
        bf16x8 af2 = *(const bf16x8*)(const void*)(hp + 64);
        bf16x8 af3 = *(const bf16x8*)(const void*)(hp + 96);
        f32x4 aF = nF, aI = nI, aG = nG, aO = nO;
        // per-gate chains, F first (its tail exp can start during I/G/O drain)
        aF = __builtin_amdgcn_mfma_f32_16x16x32_bf16(af0, bfr[1][0], aF, 0, 0, 0);
        aF = __builtin_amdgcn_mfma_f32_16x16x32_bf16(af1, bfr[1][1], aF, 0, 0, 0);
        aF = __builtin_amdgcn_mfma_f32_16x16x32_bf16(af2, bfr[1][2], aF, 0, 0, 0);
        aF = __builtin_amdgcn_mfma_f32_16x16x32_bf16(af3, bfr[1][3], aF, 0, 0, 0);
        aI = __builtin_amdgcn_mfma_f32_16x16x32_bf16(af0, bfr[0][0], aI, 0, 0, 0);
        aI = __builtin_amdgcn_mfma_f32_16x16x32_bf16(af1, bfr[0][1], aI, 0, 0, 0);
        aI = __builtin_amdgcn_mfma_f32_16x16x32_bf16(af2, bfr[0][2], aI, 0, 0, 0);
        aI = __builtin_amdgcn_mfma_f32_16x16x32_bf16(af3, bfr[0][3], aI, 0, 0, 0);
        aG = __builtin_amdgcn_mfma_f32_16x16x32_bf16(af0, bfr[2][0], aG, 0, 0, 0);
        aG = __builtin_amdgcn_mfma_f32_16x16x32_bf16(af1, bfr[2][1], aG, 0, 0, 0);
        aG = __builtin_amdgcn_mfma_f32_16x16x32_bf16(af2, bfr[2][2], aG, 0, 0, 0);
        aG = __builtin_amdgcn_mfma_f32_16x16x32_bf16(af3, bfr[2][3], aG, 0, 0, 0);
        aO = __builtin_amdgcn_mfma_f32_16x16x32_bf16(af0, bfr[3][0], aO, 0, 0, 0);
        aO = __builtin_amdgcn_mfma_f32_16x16x32_bf16(af1, bfr[3][1], aO, 0, 0, 0);
        aO = __builtin_amdgcn_mfma_f32_16x16x32_bf16(af2, bfr[3][2], aO, 0, 0, 0);
        aO = __builtin_amdgcn_mfma_f32_16x16x32_bf16(af3, bfr[3][3], aO, 0, 0, 0);
        // next-step acc-init in the MFMA shadow (independent of h)
        {
            f32x4 xq = *(const f32x4*)(const void*)(xls + (t + 1) * 16 + quad * 4);
            #pragma unroll
            for (int r = 0; r < 4; ++r) {
                nI[r] = xq[r] * ag[0] + bg[0];
                nF[r] = xq[r] * ag[1] + bg[1];
                nG[r] = xq[r] * ag[2] + bg[2];
                nO[r] = xq[r] * ag[3] + bg[3];
            }
        }
        // tail: early exp batches (F, I, G), then per-row combine
        f32x4 e5v, e1v, e2v;
        #pragma unroll
        for (int r = 0; r < 4; ++r) e5v[r] = __builtin_amdgcn_exp2f(-aF[r]);
        #pragma unroll
        for (int r = 0; r < 4; ++r) e1v[r] = __builtin_amdgcn_exp2f(-aI[r]);
        #pragma unroll
        for (int r = 0; r < 4; ++r) e2v[r] = __builtin_amdgcn_exp2f(aG[r]);
        unsigned short* wp = hout + quad * 4 * HSTR + m0 + lcol;
        #pragma unroll
        for (int r = 0; r < 4; ++r) {
            float sf = __builtin_amdgcn_rcpf(1.0f + e5v[r]);                 // sig(f)
            float pp = (e2v[r] - 1.0f) *
                       __builtin_amdgcn_rcpf((1.0f + e1v[r]) * (e2v[r] + 1.0f)); // sig(i)tanh(g)
            float c2 = sf * cst[r] + pp;
            cst[r] = c2;
            float e3 = __builtin_amdgcn_exp2f(c2 * TL2E);
            float e4 = __builtin_amdgcn_exp2f(-aO[r]);
            float h  = (e3 - 1.0f) * __builtin_amdgcn_rcpf((1.0f + e4) * (e3 + 1.0f));
            wp[r * HSTR] = __builtin_bit_cast(unsigned short, (__bf16)h);
        }
        __syncthreads();
    };
    for (int t = 0; t < 128; t += 2) {
        step(t,     hbuf[0], hbuf[1]);
        step(t + 1, hbuf[1], hbuf[0]);
    }
    // final h in hbuf[0]; final c in cst

    // ---- per-block partials ----
    {
        float hv = 0.f;
        #pragma unroll
        for (int r = 0; r < 4; ++r)
            hv += (float)__builtin_bit_cast(__bf16, hbuf[0][(quad * 4 + r) * HSTR + m0 + lcol]);
        hv += __shfl_xor(hv, 16);
        hv += __shfl_xor(hv, 32);
        if (lane < 16) partials[blockIdx.x * 256 + m0 + lane] = hv;
    }
    {
        f32x4 facc;
        float bb = b_fh[m0 + lcol] * L2E;
        #pragma unroll
        for (int r = 0; r < 4; ++r) facc[r] = bb;
        #pragma unroll
        for (int kk = 0; kk < 4; ++kk) {
            bf16x8 afr = *(const bf16x8*)(const void*)(hbuf[0] + lcol * HSTR + kk * 32 + quad * 8);
            const float* p = W_fh + (m0 + lcol) * 128 + kk * 32 + quad * 8;
            f32x4 w0 = *(const f32x4*)p;
            f32x4 w1 = *(const f32x4*)(p + 4);
            bf16x8 wt;
            #pragma unroll
            for (int q = 0; q < 4; ++q) {
                wt[q]     = (__bf16)(w0[q] * L2E);
                wt[q + 4] = (__bf16)(w1[q] * L2E);
            }
            facc = __builtin_amdgcn_mfma_f32_16x16x32_bf16(afr, wt, facc, 0, 0, 0);
        }
        float fcv = 0.f;
        #pragma unroll
        for (int r = 0; r < 4; ++r) fcv += sig2(facc[r]) * cst[r];
        fcv += __shfl_xor(fcv, 16);
        fcv += __shfl_xor(fcv, 32);
        if (lane < 16) partials[blockIdx.x * 256 + 128 + m0 + lane] = fcv;
    }

    // ---- last-arrival block performs the finalize ----
    __threadfence();
    __syncthreads();
    if (tid == 0) s_last = atomicAdd(flag, 1);
    __syncthreads();
    if (s_last != 255) return;
    __threadfence();

    {
        int j = tid & 255;
        int half = tid >> 8;
        const float* p = partials + half * 128 * 256 + j;
        float s0 = 0.f, s1 = 0.f, s2 = 0.f, s3 = 0.f;
        #pragma unroll 2
        for (int b = 0; b < 128; b += 4) {
            s0 += p[(b + 0) * 256];
            s1 += p[(b + 1) * 256];
            s2 += p[(b + 2) * 256];
            s3 += p[(b + 3) * 256];
        }
        float s = (s0 + s1) + (s2 + s3);
        if (half == 0) fin[j] = s;
        __syncthreads();
        if (half == 1) fin[j] += s;
    }
    __syncthreads();
    if (tid < 384) {
        float s = b_iouh[tid];
        const f32x4* row = (const f32x4*)(W_iouh + tid * 128);
        #pragma unroll 8
        for (int m = 0; m < 32; ++m) {
            f32x4 w = row[m];
            s += w[0]*fin[4*m] + w[1]*fin[4*m+1] + w[2]*fin[4*m+2] + w[3]*fin[4*m+3];
        }
        fin[256 + tid] = s;
    }
    __syncthreads();
    if (tid < 128) {
        float i = fin[256 + tid], o = fin[384 + tid], u = fin[512 + tid];
        float cf = sig2(i * L2E) * (2.0f * sig2(u * TL2E) - 1.0f) + fin[128 + tid];
        out[tid] = cf;
        fin[640 + tid] = sig2(o * L2E) * (2.0f * sig2(cf * TL2E) - 1.0f);
    }
    __syncthreads();
    if (tid < 128) {
        float s = b_lout[tid];
        const f32x4* row = (const f32x4*)(W_lout + tid * 128);
        #pragma unroll 8
        for (int m = 0; m < 32; ++m) {
            f32x4 w = row[m];
            s += w[0]*fin[640+4*m] + w[1]*fin[641+4*m] + w[2]*fin[642+4*m] + w[3]*fin[643+4*m];
        }
        out[128 + tid] = s;
    }
}

extern "C" void kernel_launch(void* const* d_in, const int* in_sizes, int n_in,
                              void* d_out, int out_size, void* d_ws, size_t ws_size,
                              hipStream_t stream) {
    const float* numbers = (const float*)d_in[0];
    const float* w_num   = (const float*)d_in[1];
    const float* b_num   = (const float*)d_in[2];
    const float* W_ih    = (const float*)d_in[3];
    const float* W_hh    = (const float*)d_in[4];
    const float* b_ih    = (const float*)d_in[5];
    const float* b_hh    = (const float*)d_in[6];
    const float* W_fh    = (const float*)d_in[7];
    const float* b_fh    = (const float*)d_in[8];
    const float* W_iouh  = (const float*)d_in[9];
    const float* b_iouh  = (const float*)d_in[10];
    const float* W_lout  = (const float*)d_in[11];
    const float* b_lout  = (const float*)d_in[12];
    float* out = (float*)d_out;

    float* partials = (float*)d_ws;               // 256 blocks x 256 floats
    int*   flag     = (int*)((float*)d_ws + 256 * 256);

    hipMemsetAsync(flag, 0, sizeof(int), stream);
    lstm_kernel<<<256, 512, 0, stream>>>(numbers, w_num, b_num, W_ih, W_hh,
                                         b_ih, b_hh, W_fh, b_fh,
                                         W_iouh, b_iouh, W_lout, b_lout,
                                         partials, flag, out);
}